// Round 8
// baseline (106.717 us; speedup 1.0000x reference)
//
#include <hip/hip_runtime.h>

typedef __attribute__((ext_vector_type(8))) short bf16x8;
typedef __attribute__((ext_vector_type(4))) float f32x4;
typedef __attribute__((ext_vector_type(2))) unsigned int u32x2;
typedef __attribute__((ext_vector_type(4))) unsigned int u32x4;

__device__ __forceinline__ unsigned short f2bf(float f) {
  return __builtin_bit_cast(unsigned short, (__bf16)f);
}
__device__ __forceinline__ unsigned pk2(float a, float b) {
  return (unsigned)f2bf(a) | ((unsigned)f2bf(b) << 16);
}
__device__ __forceinline__ bf16x8 frag(u32x4 v) { return __builtin_bit_cast(bf16x8, v); }

// wave-level compiler memory fence (cross-lane LDS handoff within a wave)
__device__ __forceinline__ void wfence() {
  asm volatile("" ::: "memory");
  __builtin_amdgcn_wave_barrier();
}

#define MFMA16(a, b, c) __builtin_amdgcn_mfma_f32_16x16x32_bf16(a, b, c, 0, 0, 0)

#define LR 72            // 64-col rows, 144 B stride: 16B-aligned, bank-rotating
#define OFF_VT 4608      // per-elem: K rows at 0; VT at 4608; Q (-> attn) at 9216
#define OFF_Q  9216
#define ELDS   13824     // ushorts per batch element
#define ZOK    64        // 16B zero block in elem0 K row-0 padding
#define LDS_TOT (2 * ELDS)   // 55,296 B -> 2 blocks/CU

// ---- weight prep (identical to R5/R6 -- numerically validated) ----
// pi k-permutation: slot(ks,g,j) -> source col 16*(2ks + (j>>2)) + 4g + (j&3).
// chunks (1 KB each): [0,8)=WqT(pi, x0.125*log2e) [8,16)=WkT(pi) [16,24)=Wv(pi)
// [24,32)=WpT(natural) [32,64)=W1T(pi) [64,96)=W2T(pi per 64-chunk)
__global__ void prep_weights(const float* __restrict__ wq, const float* __restrict__ wk,
                             const float* __restrict__ wv, const float* __restrict__ projw,
                             const float* __restrict__ fc1w, const float* __restrict__ fc2w,
                             unsigned short* __restrict__ ws) {
  int c = blockIdx.x, l = threadIdx.x;
  int g = l >> 4, jl = l & 15;
  int kind, T, ks;
  if (c < 8)       { kind = 0; T = c >> 1;        ks = c & 1; }
  else if (c < 16) { kind = 1; T = (c - 8) >> 1;  ks = (c - 8) & 1; }
  else if (c < 24) { kind = 2; T = (c - 16) >> 1; ks = (c - 16) & 1; }
  else if (c < 32) { kind = 3; T = (c - 24) >> 1; ks = (c - 24) & 1; }
  else if (c < 64) { kind = 4; T = (c - 32) >> 1; ks = (c - 32) & 1; }
  else             { kind = 5; T = (c - 64) >> 3; ks = (c - 64) & 7; }
  int n = 16 * T + jl;
  unsigned short* dst = ws + c * 512 + l * 8;
  #pragma unroll
  for (int jj = 0; jj < 8; ++jj) {
    int kp = 16 * (2 * (ks & 1) + (jj >> 2)) + 4 * g + (jj & 3);   // pi slot->col
    int kn = 32 * ks + 8 * g + jj;                                  // natural
    float v;
    if (kind == 0)      v = wq[(n >> 3) * 512 + kp * 8 + (n & 7)] * 0.18033688011f;
    else if (kind == 1) v = wk[(n >> 3) * 512 + kp * 8 + (n & 7)];
    else if (kind == 2) v = wv[(n >> 3) * 512 + kp * 8 + (n & 7)];
    else if (kind == 3) v = projw[kn * 64 + n];
    else if (kind == 4) v = fc1w[kp * 256 + n];
    else                v = fc2w[(64 * (ks >> 1) + kp) * 64 + n];
    dst[jj] = f2bf(v);
  }
}

__device__ __forceinline__ bf16x8 ldw(const unsigned short* __restrict__ wsm,
                                      int chunk, int lane) {
  return *(const bf16x8*)(wsm + chunk * 512 + lane * 8);
}

// Each wave owns token rows 16w..16w+15 of TWO batch elements: every weight
// fragment load feeds two MFMAs, and the two independent dependency chains
// give the scheduler intra-wave ILP to hide L2/LDS latency.
__global__ __launch_bounds__(256, 2) void block_fused(
    const float* __restrict__ x,
    const float* __restrict__ ln1w, const float* __restrict__ ln1b,
    const float* __restrict__ projb,
    const float* __restrict__ ln2w, const float* __restrict__ ln2b,
    const float* __restrict__ fc1b, const float* __restrict__ fc2b,
    const unsigned short* __restrict__ wsm, float* __restrict__ out) {
  __shared__ __attribute__((aligned(16))) unsigned short lds[LDS_TOT];

  const int tid  = threadIdx.x;
  const int w    = tid >> 6;     // wave 0..3 owns tokens 16w..16w+15
  const int lane = tid & 63;
  const int g    = lane >> 4;
  const int jl   = lane & 15;
  const size_t b = blockIdx.x;   // pair index
  const float* xbe[2] = {x + (2 * b) * 4096, x + (2 * b + 1) * 4096};
  const f32x4 zf = {0.f, 0.f, 0.f, 0.f};

  const int myrow = 16 * w + jl;                 // this lane's token
  const int sigb  = 32 * (w >> 1) + 8 * g + 4 * (w & 1);  // sigma slot base for V

  // ---------- LN1 (both elems) fully in registers ----------
  bf16x8 hb0[2], hb1[2];
  {
    f32x4 lw1[4], lb1[4];
    #pragma unroll
    for (int mi = 0; mi < 4; ++mi) {
      lw1[mi] = *(const f32x4*)(ln1w + 16 * mi + 4 * g);
      lb1[mi] = *(const f32x4*)(ln1b + 16 * mi + 4 * g);
    }
    #pragma unroll
    for (int e = 0; e < 2; ++e) {
      f32x4 xw[4];
      float s = 0.f, ss = 0.f;
      #pragma unroll
      for (int mi = 0; mi < 4; ++mi) {
        xw[mi] = *(const f32x4*)(xbe[e] + myrow * 64 + 16 * mi + 4 * g);
        #pragma unroll
        for (int r = 0; r < 4; ++r) { s += xw[mi][r]; ss += xw[mi][r] * xw[mi][r]; }
      }
      s  += __shfl_xor(s, 16, 64);  s  += __shfl_xor(s, 32, 64);
      ss += __shfl_xor(ss, 16, 64); ss += __shfl_xor(ss, 32, 64);
      float mean = s * 0.015625f;
      float rstd = rsqrtf(ss * 0.015625f - mean * mean + 1e-5f);
      unsigned hr[8];
      #pragma unroll
      for (int mi = 0; mi < 4; ++mi) {
        float o0 = (xw[mi][0] - mean) * rstd * lw1[mi][0] + lb1[mi][0];
        float o1 = (xw[mi][1] - mean) * rstd * lw1[mi][1] + lb1[mi][1];
        float o2 = (xw[mi][2] - mean) * rstd * lw1[mi][2] + lb1[mi][2];
        float o3 = (xw[mi][3] - mean) * rstd * lw1[mi][3] + lb1[mi][3];
        hr[2 * mi] = pk2(o0, o1); hr[2 * mi + 1] = pk2(o2, o3);
      }
      hb0[e] = frag((u32x4){hr[0], hr[1], hr[2], hr[3]});
      hb1[e] = frag((u32x4){hr[4], hr[5], hr[6], hr[7]});
    }
  }

  // ---------- QKV: each weight frag feeds both elems ----------
  #pragma unroll
  for (int mt = 0; mt < 4; ++mt) {
    bf16x8 aq0 = ldw(wsm, 0 + 2 * mt, lane),  aq1 = ldw(wsm, 1 + 2 * mt, lane);
    bf16x8 ak0 = ldw(wsm, 8 + 2 * mt, lane),  ak1 = ldw(wsm, 9 + 2 * mt, lane);
    bf16x8 bv0 = ldw(wsm, 16 + 2 * mt, lane), bv1 = ldw(wsm, 17 + 2 * mt, lane);
    #pragma unroll
    for (int e = 0; e < 2; ++e) {
      unsigned short* L = lds + e * ELDS;
      f32x4 q = MFMA16(aq0, hb0[e], zf); q = MFMA16(aq1, hb1[e], q);
      *(u32x2*)(L + OFF_Q + myrow * LR + 16 * mt + 4 * g) =
          (u32x2){pk2(q[0], q[1]), pk2(q[2], q[3])};
      f32x4 kk = MFMA16(ak0, hb0[e], zf); kk = MFMA16(ak1, hb1[e], kk);
      *(u32x2*)(L + myrow * LR + 16 * mt + 4 * g) =
          (u32x2){pk2(kk[0], kk[1]), pk2(kk[2], kk[3])};
      // V non-swapped: lane holds V[16w+4g+r][16mt+jl] -> VT row 16mt+jl, sigma slot
      f32x4 vv = MFMA16(hb0[e], bv0, zf); vv = MFMA16(hb1[e], bv1, vv);
      *(u32x2*)(L + OFF_VT + (16 * mt + jl) * LR + sigb) =
          (u32x2){pk2(vv[0], vv[1]), pk2(vv[2], vv[3])};
    }
  }
  if (tid == 0) *(u32x4*)(lds + ZOK) = (u32x4){0u, 0u, 0u, 0u};
  __syncthreads();   // the ONLY barrier: publish K, VT (Q rows are wave-private)

  // ---------- attention: two independent chains per head ----------
  #pragma unroll
  for (int h = 0; h < 8; ++h) {
    #pragma unroll
    for (int e = 0; e < 2; ++e) {
      const unsigned short* L = lds + e * ELDS;
      bf16x8 bq = *(const bf16x8*)(((g == 0) ? (L + OFF_Q + myrow * LR + 8 * h) : (lds + ZOK)));
      unsigned Up[8];
      float sum = 0.f;
      #pragma unroll
      for (int mi = 0; mi < 4; ++mi) {
        if (mi <= w) {   // wave-uniform causal tile skip
          bf16x8 ak = *(const bf16x8*)(((g == 0) ? (L + (16 * mi + jl) * LR + 8 * h) : (lds + ZOK)));
          f32x4 sc = MFMA16(ak, bq, zf);
          float e0 = exp2f(sc[0]), e1 = exp2f(sc[1]);
          float e2 = exp2f(sc[2]), e3 = exp2f(sc[3]);
          if (mi == w) {   // diagonal: keep s<=q  <=>  4g+r <= jl
            e0 = (4 * g + 0 <= jl) ? e0 : 0.f;
            e1 = (4 * g + 1 <= jl) ? e1 : 0.f;
            e2 = (4 * g + 2 <= jl) ? e2 : 0.f;
            e3 = (4 * g + 3 <= jl) ? e3 : 0.f;
          }
          sum += (e0 + e1) + (e2 + e3);
          Up[2 * mi] = pk2(e0, e1); Up[2 * mi + 1] = pk2(e2, e3);
        } else { Up[2 * mi] = 0u; Up[2 * mi + 1] = 0u; }
      }
      sum += __shfl_xor(sum, 16, 64);
      sum += __shfl_xor(sum, 32, 64);
      float inv = __builtin_amdgcn_rcpf(sum);
      bf16x8 bp0 = frag((u32x4){Up[0], Up[1], Up[2], Up[3]});   // pi-slots = sigma tokens
      bf16x8 bp1 = frag((u32x4){Up[4], Up[5], Up[6], Up[7]});
      const unsigned short* vtr = L + OFF_VT + (8 * h + jl) * LR;
      bf16x8 aw0 = *(const bf16x8*)((jl < 8) ? (vtr + 8 * g) : (lds + ZOK));
      bf16x8 aw1 = *(const bf16x8*)((jl < 8) ? (vtr + 32 + 8 * g) : (lds + ZOK));
      f32x4 pv = MFMA16(aw0, bp0, zf); pv = MFMA16(aw1, bp1, pv);
      if (g < 2)   // attn[myrow][8h+4g+{0..3}] -> dead Q slice of own row
        *(u32x2*)(lds + e * ELDS + OFF_Q + myrow * LR + 8 * h + 4 * g) =
            (u32x2){pk2(pv[0] * inv, pv[1] * inv), pk2(pv[2] * inv, pv[3] * inv)};
    }
  }
  wfence();   // predicated (g<2) attn stores -> all-lane bat reads (cross-lane)
  bf16x8 bat0[2], bat1[2];
  #pragma unroll
  for (int e = 0; e < 2; ++e) {
    bat0[e] = *(const bf16x8*)(lds + e * ELDS + OFF_Q + myrow * LR + 8 * g);
    bat1[e] = *(const bf16x8*)(lds + e * ELDS + OFF_Q + myrow * LR + 32 + 8 * g);
  }

  // ---------- proj (swapped, natural k) + residual; x2 in fp32 regs ----------
  f32x4 x2[2][4];
  #pragma unroll
  for (int mi = 0; mi < 4; ++mi) {
    bf16x8 a0 = ldw(wsm, 24 + 2 * mi, lane);
    bf16x8 a1 = ldw(wsm, 25 + 2 * mi, lane);
    f32x4 pb = *(const f32x4*)(projb + 16 * mi + 4 * g);
    #pragma unroll
    for (int e = 0; e < 2; ++e) {
      f32x4 acc = MFMA16(a0, bat0[e], zf); acc = MFMA16(a1, bat1[e], acc);
      f32x4 xv = *(const f32x4*)(xbe[e] + myrow * 64 + 16 * mi + 4 * g);
      x2[e][mi] = xv + acc + pb;
    }
  }

  // ---------- LN2 (both elems) in registers ----------
  bf16x8 hc0[2], hc1[2];
  {
    f32x4 lw2[4], lb2[4];
    #pragma unroll
    for (int mi = 0; mi < 4; ++mi) {
      lw2[mi] = *(const f32x4*)(ln2w + 16 * mi + 4 * g);
      lb2[mi] = *(const f32x4*)(ln2b + 16 * mi + 4 * g);
    }
    #pragma unroll
    for (int e = 0; e < 2; ++e) {
      float s = 0.f, ss = 0.f;
      #pragma unroll
      for (int mi = 0; mi < 4; ++mi)
        #pragma unroll
        for (int r = 0; r < 4; ++r) { s += x2[e][mi][r]; ss += x2[e][mi][r] * x2[e][mi][r]; }
      s  += __shfl_xor(s, 16, 64);  s  += __shfl_xor(s, 32, 64);
      ss += __shfl_xor(ss, 16, 64); ss += __shfl_xor(ss, 32, 64);
      float mean2 = s * 0.015625f;
      float rstd2 = rsqrtf(ss * 0.015625f - mean2 * mean2 + 1e-5f);
      unsigned h2[8];
      #pragma unroll
      for (int mi = 0; mi < 4; ++mi) {
        float o0 = (x2[e][mi][0] - mean2) * rstd2 * lw2[mi][0] + lb2[mi][0];
        float o1 = (x2[e][mi][1] - mean2) * rstd2 * lw2[mi][1] + lb2[mi][1];
        float o2 = (x2[e][mi][2] - mean2) * rstd2 * lw2[mi][2] + lb2[mi][2];
        float o3 = (x2[e][mi][3] - mean2) * rstd2 * lw2[mi][3] + lb2[mi][3];
        h2[2 * mi] = pk2(o0, o1); h2[2 * mi + 1] = pk2(o2, o3);
      }
      hc0[e] = frag((u32x4){h2[0], h2[1], h2[2], h2[3]});
      hc1[e] = frag((u32x4){h2[4], h2[5], h2[6], h2[7]});
    }
  }

  // ---------- FF: each weight frag feeds both elems ----------
  f32x4 acc2[2][4];
  #pragma unroll
  for (int e = 0; e < 2; ++e)
    #pragma unroll
    for (int mi = 0; mi < 4; ++mi) acc2[e][mi] = zf;
  #pragma unroll
  for (int c = 0; c < 4; ++c) {
    unsigned fr[2][8];
    #pragma unroll
    for (int ml = 0; ml < 4; ++ml) {      // fc1 (swapped): hidden tile T
      int T = 4 * c + ml;
      bf16x8 a0 = ldw(wsm, 32 + 2 * T, lane);
      bf16x8 a1 = ldw(wsm, 33 + 2 * T, lane);
      f32x4 bb = *(const f32x4*)(fc1b + 16 * T + 4 * g);
      #pragma unroll
      for (int e = 0; e < 2; ++e) {
        f32x4 acc = MFMA16(a0, hc0[e], zf); acc = MFMA16(a1, hc1[e], acc);
        fr[e][2 * ml]     = pk2(fmaxf(acc[0] + bb[0], 0.f), fmaxf(acc[1] + bb[1], 0.f));
        fr[e][2 * ml + 1] = pk2(fmaxf(acc[2] + bb[2], 0.f), fmaxf(acc[3] + bb[3], 0.f));
      }
    }
    bf16x8 bf0[2], bf1[2];
    #pragma unroll
    for (int e = 0; e < 2; ++e) {
      bf0[e] = frag((u32x4){fr[e][0], fr[e][1], fr[e][2], fr[e][3]});
      bf1[e] = frag((u32x4){fr[e][4], fr[e][5], fr[e][6], fr[e][7]});
    }
    #pragma unroll
    for (int mi = 0; mi < 4; ++mi) {      // fc2 (swapped): accumulate cout tiles
      bf16x8 w20 = ldw(wsm, 64 + 8 * mi + 2 * c, lane);
      bf16x8 w21 = ldw(wsm, 65 + 8 * mi + 2 * c, lane);
      #pragma unroll
      for (int e = 0; e < 2; ++e) {
        acc2[e][mi] = MFMA16(w20, bf0[e], acc2[e][mi]);
        acc2[e][mi] = MFMA16(w21, bf1[e], acc2[e][mi]);
      }
    }
  }

  // ---------- epilogue ----------
  #pragma unroll
  for (int mi = 0; mi < 4; ++mi) {
    f32x4 fb = *(const f32x4*)(fc2b + 16 * mi + 4 * g);
    #pragma unroll
    for (int e = 0; e < 2; ++e) {
      float* ob = out + (2 * b + e) * 4096 + myrow * 64;
      f32x4 o = x2[e][mi] + acc2[e][mi] + fb;
      *(f32x4*)(ob + 16 * mi + 4 * g) = o;
    }
  }
}

extern "C" void kernel_launch(void* const* d_in, const int* in_sizes, int n_in,
                              void* d_out, int out_size, void* d_ws, size_t ws_size,
                              hipStream_t stream) {
  const float* x     = (const float*)d_in[0];
  const float* ln1w  = (const float*)d_in[1];
  const float* ln1b  = (const float*)d_in[2];
  const float* wq    = (const float*)d_in[3];
  const float* wk    = (const float*)d_in[4];
  const float* wvp   = (const float*)d_in[5];
  const float* projw = (const float*)d_in[6];
  const float* projb = (const float*)d_in[7];
  const float* ln2w  = (const float*)d_in[8];
  const float* ln2b  = (const float*)d_in[9];
  const float* fc1w  = (const float*)d_in[10];
  const float* fc1b  = (const float*)d_in[11];
  const float* fc2w  = (const float*)d_in[12];
  const float* fc2b  = (const float*)d_in[13];
  unsigned short* ws = (unsigned short*)d_ws;   // 96 KB repacked weights
  float* out = (float*)d_out;

  prep_weights<<<dim3(96), dim3(64), 0, stream>>>(wq, wk, wvp, projw, fc1w, fc2w, ws);

  int nblk = in_sizes[0] / 8192;   // pairs of batch elements
  block_fused<<<dim3(nblk), dim3(256), 0, stream>>>(
      x, ln1w, ln1b, projb, ln2w, ln2b, fc1b, fc2b, ws, out);
}

// Round 9
// 104.937 us; speedup vs baseline: 1.0170x; 1.0170x over previous
//
#include <hip/hip_runtime.h>

typedef __attribute__((ext_vector_type(8))) short bf16x8;
typedef __attribute__((ext_vector_type(4))) float f32x4;
typedef __attribute__((ext_vector_type(2))) unsigned int u32x2;
typedef __attribute__((ext_vector_type(4))) unsigned int u32x4;

__device__ __forceinline__ unsigned short f2bf(float f) {
  return __builtin_bit_cast(unsigned short, (__bf16)f);
}
__device__ __forceinline__ unsigned pk2(float a, float b) {
  return (unsigned)f2bf(a) | ((unsigned)f2bf(b) << 16);
}
__device__ __forceinline__ bf16x8 frag(u32x4 v) { return __builtin_bit_cast(bf16x8, v); }

// wave-level compiler memory fence (cross-lane LDS handoff within a wave)
__device__ __forceinline__ void wfence() {
  asm volatile("" ::: "memory");
  __builtin_amdgcn_wave_barrier();
}

#define MFMA16(a, b, c) __builtin_amdgcn_mfma_f32_16x16x32_bf16(a, b, c, 0, 0, 0)

#define LR 72            // 64-col rows, 144 B stride: 16B-aligned, bank-rotating
#define OFF_VT 4608      // K rows at 0; VT rows at 4608; Q (-> attn) rows at 9216
#define OFF_Q  9216
#define ZOK 64           // 16B zero block in K row-0 padding
#define LDS_TOT 13824    // ushorts = 27,648 B -> 5 blocks/CU

// ---- weight prep (identical to R5/R6 -- numerically validated) ----
// pi k-permutation: slot(ks,g,j) -> source col 16*(2ks + (j>>2)) + 4g + (j&3).
// chunks (1 KB each): [0,8)=WqT(pi, x0.125*log2e) [8,16)=WkT(pi) [16,24)=Wv(pi)
// [24,32)=WpT(natural) [32,64)=W1T(pi) [64,96)=W2T(pi per 64-chunk)
__global__ void prep_weights(const float* __restrict__ wq, const float* __restrict__ wk,
                             const float* __restrict__ wv, const float* __restrict__ projw,
                             const float* __restrict__ fc1w, const float* __restrict__ fc2w,
                             unsigned short* __restrict__ ws) {
  int c = blockIdx.x, l = threadIdx.x;
  int g = l >> 4, jl = l & 15;
  int kind, T, ks;
  if (c < 8)       { kind = 0; T = c >> 1;        ks = c & 1; }
  else if (c < 16) { kind = 1; T = (c - 8) >> 1;  ks = (c - 8) & 1; }
  else if (c < 24) { kind = 2; T = (c - 16) >> 1; ks = (c - 16) & 1; }
  else if (c < 32) { kind = 3; T = (c - 24) >> 1; ks = (c - 24) & 1; }
  else if (c < 64) { kind = 4; T = (c - 32) >> 1; ks = (c - 32) & 1; }
  else             { kind = 5; T = (c - 64) >> 3; ks = (c - 64) & 7; }
  int n = 16 * T + jl;
  unsigned short* dst = ws + c * 512 + l * 8;
  #pragma unroll
  for (int jj = 0; jj < 8; ++jj) {
    int kp = 16 * (2 * (ks & 1) + (jj >> 2)) + 4 * g + (jj & 3);   // pi slot->col
    int kn = 32 * ks + 8 * g + jj;                                  // natural
    float v;
    if (kind == 0)      v = wq[(n >> 3) * 512 + kp * 8 + (n & 7)] * 0.18033688011f;
    else if (kind == 1) v = wk[(n >> 3) * 512 + kp * 8 + (n & 7)];
    else if (kind == 2) v = wv[(n >> 3) * 512 + kp * 8 + (n & 7)];
    else if (kind == 3) v = projw[kn * 64 + n];
    else if (kind == 4) v = fc1w[kp * 256 + n];
    else                v = fc2w[(64 * (ks >> 1) + kp) * 64 + n];
    dst[jj] = f2bf(v);
  }
}

__global__ __launch_bounds__(256, 5) void block_fused(
    const float* __restrict__ x,
    const float* __restrict__ ln1w, const float* __restrict__ ln1b,
    const float* __restrict__ projb,
    const float* __restrict__ ln2w, const float* __restrict__ ln2b,
    const float* __restrict__ fc1b, const float* __restrict__ fc2b,
    const unsigned short* __restrict__ wsm, float* __restrict__ out) {
  __shared__ __attribute__((aligned(16))) unsigned short lds[LDS_TOT];

  const int tid  = threadIdx.x;
  const int w    = tid >> 6;     // wave 0..3 owns tokens 16w..16w+15
  const int lane = tid & 63;
  const int g    = lane >> 4;
  const int jl   = lane & 15;
  const size_t b = blockIdx.x;
  const float* xb = x + b * 4096;
  const f32x4 zf = {0.f, 0.f, 0.f, 0.f};

  const int myrow = 16 * w + jl;                 // this lane's token
  const int krow  = myrow * LR;                  // K region row
  const int qrow  = OFF_Q + myrow * LR;          // Q (-> attn) region row
  const int sigb  = 32 * (w >> 1) + 8 * g + 4 * (w & 1);  // sigma slot base for V

  if (tid == 0) *(u32x4*)(lds + ZOK) = (u32x4){0u, 0u, 0u, 0u};

  // ---------- LN1 fully in registers ----------
  float mean, rstd;
  unsigned hr[8];
  {
    f32x4 xw[4];
    float s = 0.f, ss = 0.f;
    #pragma unroll
    for (int mi = 0; mi < 4; ++mi) {
      xw[mi] = *(const f32x4*)(xb + myrow * 64 + 16 * mi + 4 * g);
      #pragma unroll
      for (int r = 0; r < 4; ++r) { s += xw[mi][r]; ss += xw[mi][r] * xw[mi][r]; }
    }
    s  += __shfl_xor(s, 16, 64);  s  += __shfl_xor(s, 32, 64);
    ss += __shfl_xor(ss, 16, 64); ss += __shfl_xor(ss, 32, 64);
    mean = s * 0.015625f;
    rstd = rsqrtf(ss * 0.015625f - mean * mean + 1e-5f);
    #pragma unroll
    for (int mi = 0; mi < 4; ++mi) {
      f32x4 lw = *(const f32x4*)(ln1w + 16 * mi + 4 * g);
      f32x4 lb = *(const f32x4*)(ln1b + 16 * mi + 4 * g);
      float o0 = (xw[mi][0] - mean) * rstd * lw[0] + lb[0];
      float o1 = (xw[mi][1] - mean) * rstd * lw[1] + lb[1];
      float o2 = (xw[mi][2] - mean) * rstd * lw[2] + lb[2];
      float o3 = (xw[mi][3] - mean) * rstd * lw[3] + lb[3];
      hr[2 * mi] = pk2(o0, o1); hr[2 * mi + 1] = pk2(o2, o3);
    }
  }
  bf16x8 hb0 = frag((u32x4){hr[0], hr[1], hr[2], hr[3]});   // pi-layout B-frag ks=0
  bf16x8 hb1 = frag((u32x4){hr[4], hr[5], hr[6], hr[7]});   // ks=1

  // ---------- QKV (rolled): Q->LDS, K->LDS, V->LDS VT (sigma slots) ----------
  #pragma clang loop unroll(disable)
  for (int mt = 0; mt < 4; ++mt) {
    const unsigned short* wq8 = wsm + (2 * mt) * 512 + lane * 8;
    bf16x8 aq0 = *(const bf16x8*)(wq8);
    bf16x8 aq1 = *(const bf16x8*)(wq8 + 512);
    bf16x8 ak0 = *(const bf16x8*)(wq8 + 8 * 512);
    bf16x8 ak1 = *(const bf16x8*)(wq8 + 9 * 512);
    bf16x8 bv0 = *(const bf16x8*)(wq8 + 16 * 512);
    bf16x8 bv1 = *(const bf16x8*)(wq8 + 17 * 512);
    f32x4 q = MFMA16(aq0, hb0, zf); q = MFMA16(aq1, hb1, q);
    *(u32x2*)(lds + qrow + 16 * mt + 4 * g) = (u32x2){pk2(q[0], q[1]), pk2(q[2], q[3])};
    f32x4 kk = MFMA16(ak0, hb0, zf); kk = MFMA16(ak1, hb1, kk);
    *(u32x2*)(lds + krow + 16 * mt + 4 * g) = (u32x2){pk2(kk[0], kk[1]), pk2(kk[2], kk[3])};
    // V non-swapped: lane holds V[16w+4g+r][16mt+jl] -> VT row 16mt+jl, sigma slot
    f32x4 vv = MFMA16(hb0, bv0, zf); vv = MFMA16(hb1, bv1, vv);
    *(u32x2*)(lds + OFF_VT + (16 * mt + jl) * LR + sigb) =
        (u32x2){pk2(vv[0], vv[1]), pk2(vv[2], vv[3])};
  }
  __syncthreads();   // the ONLY barrier: publish K, VT (Q rows are wave-private)

  // ---------- attention (rolled over heads) ----------
  {
    const bool g0 = (g == 0), j8 = (jl < 8);
    // diagonal causal masks, h-invariant: keep s<=q <=> 4g+r <= jl
    const bool m0 = (4 * g + 0 <= jl), m1 = (4 * g + 1 <= jl);
    const bool m2 = (4 * g + 2 <= jl), m3 = (4 * g + 3 <= jl);
    #pragma clang loop unroll(disable)
    for (int h = 0; h < 8; ++h) {
      bf16x8 bq = *(const bf16x8*)(lds + (g0 ? (qrow + 8 * h) : ZOK));
      unsigned Up0 = 0, Up1 = 0, Up2 = 0, Up3 = 0, Up4 = 0, Up5 = 0, Up6 = 0, Up7 = 0;
      float sum = 0.f;
      // mi = 0..3, wave-uniform skip mi>w; diagonal mask at mi==w
      #pragma unroll
      for (int mi = 0; mi < 4; ++mi) {
        if (mi <= w) {
          bf16x8 ak = *(const bf16x8*)(lds + (g0 ? ((16 * mi + jl) * LR + 8 * h) : ZOK));
          f32x4 sc = MFMA16(ak, bq, zf);
          float e0 = exp2f(sc[0]), e1 = exp2f(sc[1]);
          float e2 = exp2f(sc[2]), e3 = exp2f(sc[3]);
          if (mi == w) { e0 = m0 ? e0 : 0.f; e1 = m1 ? e1 : 0.f;
                         e2 = m2 ? e2 : 0.f; e3 = m3 ? e3 : 0.f; }
          sum += (e0 + e1) + (e2 + e3);
          unsigned p0 = pk2(e0, e1), p1 = pk2(e2, e3);
          if (mi == 0) { Up0 = p0; Up1 = p1; }
          else if (mi == 1) { Up2 = p0; Up3 = p1; }
          else if (mi == 2) { Up4 = p0; Up5 = p1; }
          else { Up6 = p0; Up7 = p1; }
        }
      }
      sum += __shfl_xor(sum, 16, 64);
      sum += __shfl_xor(sum, 32, 64);
      float inv = __builtin_amdgcn_rcpf(sum);
      bf16x8 bp0 = frag((u32x4){Up0, Up1, Up2, Up3});   // pi-slots = sigma tokens
      bf16x8 bp1 = frag((u32x4){Up4, Up5, Up6, Up7});
      const int vtr = OFF_VT + (8 * h + jl) * LR;
      bf16x8 aw0 = *(const bf16x8*)(lds + (j8 ? (vtr + 8 * g) : ZOK));
      bf16x8 aw1 = *(const bf16x8*)(lds + (j8 ? (vtr + 32 + 8 * g) : ZOK));
      f32x4 pv = MFMA16(aw0, bp0, zf); pv = MFMA16(aw1, bp1, pv);
      if (g < 2)   // attn[myrow][8h+4g+{0..3}] -> dead Q slice of own row
        *(u32x2*)(lds + qrow + 8 * h + 4 * g) =
            (u32x2){pk2(pv[0] * inv, pv[1] * inv), pk2(pv[2] * inv, pv[3] * inv)};
    }
  }
  wfence();   // predicated (g<2) attn stores -> all-lane bat reads (cross-lane)
  bf16x8 bat0 = *(const bf16x8*)(lds + qrow + 8 * g);
  bf16x8 bat1 = *(const bf16x8*)(lds + qrow + 32 + 8 * g);

  // ---------- proj (swapped, natural k) + residual; x2 in fp32 regs ----------
  f32x4 x2[4];
  #pragma unroll
  for (int mi = 0; mi < 4; ++mi) {
    bf16x8 a0 = *(const bf16x8*)(wsm + (24 + 2 * mi) * 512 + lane * 8);
    bf16x8 a1 = *(const bf16x8*)(wsm + (25 + 2 * mi) * 512 + lane * 8);
    f32x4 acc = MFMA16(a0, bat0, zf); acc = MFMA16(a1, bat1, acc);
    f32x4 xv = *(const f32x4*)(xb + myrow * 64 + 16 * mi + 4 * g);
    f32x4 pb = *(const f32x4*)(projb + 16 * mi + 4 * g);
    x2[mi] = xv + acc + pb;
  }

  // ---------- LN2 in registers ----------
  float mean2, rstd2;
  {
    float s = 0.f, ss = 0.f;
    #pragma unroll
    for (int mi = 0; mi < 4; ++mi)
      #pragma unroll
      for (int r = 0; r < 4; ++r) { s += x2[mi][r]; ss += x2[mi][r] * x2[mi][r]; }
    s  += __shfl_xor(s, 16, 64);  s  += __shfl_xor(s, 32, 64);
    ss += __shfl_xor(ss, 16, 64); ss += __shfl_xor(ss, 32, 64);
    mean2 = s * 0.015625f;
    rstd2 = rsqrtf(ss * 0.015625f - mean2 * mean2 + 1e-5f);
  }
  unsigned h2[8];
  #pragma unroll
  for (int mi = 0; mi < 4; ++mi) {
    f32x4 lw = *(const f32x4*)(ln2w + 16 * mi + 4 * g);
    f32x4 lb = *(const f32x4*)(ln2b + 16 * mi + 4 * g);
    float o0 = (x2[mi][0] - mean2) * rstd2 * lw[0] + lb[0];
    float o1 = (x2[mi][1] - mean2) * rstd2 * lw[1] + lb[1];
    float o2 = (x2[mi][2] - mean2) * rstd2 * lw[2] + lb[2];
    float o3 = (x2[mi][3] - mean2) * rstd2 * lw[3] + lb[3];
    h2[2 * mi] = pk2(o0, o1); h2[2 * mi + 1] = pk2(o2, o3);
  }
  bf16x8 hc0 = frag((u32x4){h2[0], h2[1], h2[2], h2[3]});
  bf16x8 hc1 = frag((u32x4){h2[4], h2[5], h2[6], h2[7]});

  // ---------- FF (rolled over 4 hidden-chunks), all registers ----------
  f32x4 acc2[4];
  #pragma unroll
  for (int mi = 0; mi < 4; ++mi) acc2[mi] = zf;
  #pragma clang loop unroll(disable)
  for (int c = 0; c < 4; ++c) {
    const unsigned short* w1c = wsm + (32 + 8 * c) * 512 + lane * 8;   // fc1 chunks
    const unsigned short* w2c = wsm + (64 + 2 * c) * 512 + lane * 8;   // fc2 chunks
    const float* b1c = fc1b + 64 * c + 4 * g;
    unsigned fr0, fr1, fr2, fr3, fr4, fr5, fr6, fr7;
    {
      bf16x8 a0 = *(const bf16x8*)(w1c);
      bf16x8 a1 = *(const bf16x8*)(w1c + 512);
      f32x4 acc = MFMA16(a0, hc0, zf); acc = MFMA16(a1, hc1, acc);
      f32x4 bb = *(const f32x4*)(b1c);
      fr0 = pk2(fmaxf(acc[0] + bb[0], 0.f), fmaxf(acc[1] + bb[1], 0.f));
      fr1 = pk2(fmaxf(acc[2] + bb[2], 0.f), fmaxf(acc[3] + bb[3], 0.f));
    }
    {
      bf16x8 a0 = *(const bf16x8*)(w1c + 2 * 512);
      bf16x8 a1 = *(const bf16x8*)(w1c + 3 * 512);
      f32x4 acc = MFMA16(a0, hc0, zf); acc = MFMA16(a1, hc1, acc);
      f32x4 bb = *(const f32x4*)(b1c + 16);
      fr2 = pk2(fmaxf(acc[0] + bb[0], 0.f), fmaxf(acc[1] + bb[1], 0.f));
      fr3 = pk2(fmaxf(acc[2] + bb[2], 0.f), fmaxf(acc[3] + bb[3], 0.f));
    }
    {
      bf16x8 a0 = *(const bf16x8*)(w1c + 4 * 512);
      bf16x8 a1 = *(const bf16x8*)(w1c + 5 * 512);
      f32x4 acc = MFMA16(a0, hc0, zf); acc = MFMA16(a1, hc1, acc);
      f32x4 bb = *(const f32x4*)(b1c + 32);
      fr4 = pk2(fmaxf(acc[0] + bb[0], 0.f), fmaxf(acc[1] + bb[1], 0.f));
      fr5 = pk2(fmaxf(acc[2] + bb[2], 0.f), fmaxf(acc[3] + bb[3], 0.f));
    }
    {
      bf16x8 a0 = *(const bf16x8*)(w1c + 6 * 512);
      bf16x8 a1 = *(const bf16x8*)(w1c + 7 * 512);
      f32x4 acc = MFMA16(a0, hc0, zf); acc = MFMA16(a1, hc1, acc);
      f32x4 bb = *(const f32x4*)(b1c + 48);
      fr6 = pk2(fmaxf(acc[0] + bb[0], 0.f), fmaxf(acc[1] + bb[1], 0.f));
      fr7 = pk2(fmaxf(acc[2] + bb[2], 0.f), fmaxf(acc[3] + bb[3], 0.f));
    }
    bf16x8 bf0 = frag((u32x4){fr0, fr1, fr2, fr3});
    bf16x8 bf1 = frag((u32x4){fr4, fr5, fr6, fr7});
    #pragma unroll
    for (int mi = 0; mi < 4; ++mi) {      // fc2 (swapped): accumulate cout tiles
      bf16x8 w20 = *(const bf16x8*)(w2c + (8 * mi) * 512);
      bf16x8 w21 = *(const bf16x8*)(w2c + (8 * mi + 1) * 512);
      acc2[mi] = MFMA16(w20, bf0, acc2[mi]);
      acc2[mi] = MFMA16(w21, bf1, acc2[mi]);
    }
  }

  // ---------- epilogue ----------
  {
    float* ob = out + b * 4096 + myrow * 64;
    #pragma unroll
    for (int mi = 0; mi < 4; ++mi) {
      f32x4 fb = *(const f32x4*)(fc2b + 16 * mi + 4 * g);
      f32x4 o = x2[mi] + acc2[mi] + fb;
      *(f32x4*)(ob + 16 * mi + 4 * g) = o;
    }
  }
}

extern "C" void kernel_launch(void* const* d_in, const int* in_sizes, int n_in,
                              void* d_out, int out_size, void* d_ws, size_t ws_size,
                              hipStream_t stream) {
  const float* x     = (const float*)d_in[0];
  const float* ln1w  = (const float*)d_in[1];
  const float* ln1b  = (const float*)d_in[2];
  const float* wq    = (const float*)d_in[3];
  const float* wk    = (const float*)d_in[4];
  const float* wvp   = (const float*)d_in[5];
  const float* projw = (const float*)d_in[6];
  const float* projb = (const float*)d_in[7];
  const float* ln2w  = (const float*)d_in[8];
  const float* ln2b  = (const float*)d_in[9];
  const float* fc1w  = (const float*)d_in[10];
  const float* fc1b  = (const float*)d_in[11];
  const float* fc2w  = (const float*)d_in[12];
  const float* fc2b  = (const float*)d_in[13];
  unsigned short* ws = (unsigned short*)d_ws;   // 96 KB repacked weights
  float* out = (float*)d_out;

  prep_weights<<<dim3(96), dim3(64), 0, stream>>>(wq, wk, wvp, projw, fc1w, fc2w, ws);

  int nblk = in_sizes[0] / 4096;
  block_fused<<<dim3(nblk), dim3(256), 0, stream>>>(
      x, ln1w, ln1b, projb, ln2w, ln2b, fc1b, fc2b, ws, out);
}

// Round 11
// 101.224 us; speedup vs baseline: 1.0543x; 1.0367x over previous
//
#include <hip/hip_runtime.h>

typedef __attribute__((ext_vector_type(8))) short bf16x8;
typedef __attribute__((ext_vector_type(4))) float f32x4;
typedef __attribute__((ext_vector_type(2))) unsigned int u32x2;
typedef __attribute__((ext_vector_type(4))) unsigned int u32x4;

__device__ __forceinline__ unsigned short f2bf(float f) {
  return __builtin_bit_cast(unsigned short, (__bf16)f);
}
__device__ __forceinline__ unsigned pk2(float a, float b) {
  return (unsigned)f2bf(a) | ((unsigned)f2bf(b) << 16);
}
__device__ __forceinline__ bf16x8 frag(u32x4 v) { return __builtin_bit_cast(bf16x8, v); }

// wave-level compiler memory fence (cross-lane LDS handoff within a wave)
__device__ __forceinline__ void wfence() {
  asm volatile("" ::: "memory");
  __builtin_amdgcn_wave_barrier();
}

#define MFMA16(a, b, c) __builtin_amdgcn_mfma_f32_16x16x32_bf16(a, b, c, 0, 0, 0)

#define LR 72            // 64-col rows, 144 B stride: 16B-aligned, bank-rotating
#define OFF_VT 4608      // K rows at 0; VT rows at 4608; Q (-> attn) rows at 9216
#define OFF_Q  9216
#define ZROW   13824     // 80-ushort zero row for disabled-lane operand reads
#define LDS_TOT 13904    // 27,808 B -> 5 blocks/CU

// ---- weight prep (identical to R5..R9 -- numerically validated) ----
// pi k-permutation: slot(ks,g,j) -> source col 16*(2ks + (j>>2)) + 4g + (j&3).
// chunks (1 KB each): [0,8)=WqT(pi, x0.125*log2e) [8,16)=WkT(pi) [16,24)=Wv(pi)
// [24,32)=WpT(natural) [32,64)=W1T(pi) [64,96)=W2T(pi per 64-chunk)
__global__ void prep_weights(const float* __restrict__ wq, const float* __restrict__ wk,
                             const float* __restrict__ wv, const float* __restrict__ projw,
                             const float* __restrict__ fc1w, const float* __restrict__ fc2w,
                             unsigned short* __restrict__ ws) {
  int c = blockIdx.x, l = threadIdx.x;
  int g = l >> 4, jl = l & 15;
  int kind, T, ks;
  if (c < 8)       { kind = 0; T = c >> 1;        ks = c & 1; }
  else if (c < 16) { kind = 1; T = (c - 8) >> 1;  ks = (c - 8) & 1; }
  else if (c < 24) { kind = 2; T = (c - 16) >> 1; ks = (c - 16) & 1; }
  else if (c < 32) { kind = 3; T = (c - 24) >> 1; ks = (c - 24) & 1; }
  else if (c < 64) { kind = 4; T = (c - 32) >> 1; ks = (c - 32) & 1; }
  else             { kind = 5; T = (c - 64) >> 3; ks = (c - 64) & 7; }
  int n = 16 * T + jl;
  unsigned short* dst = ws + c * 512 + l * 8;
  #pragma unroll
  for (int jj = 0; jj < 8; ++jj) {
    int kp = 16 * (2 * (ks & 1) + (jj >> 2)) + 4 * g + (jj & 3);   // pi slot->col
    int kn = 32 * ks + 8 * g + jj;                                  // natural
    float v;
    if (kind == 0)      v = wq[(n >> 3) * 512 + kp * 8 + (n & 7)] * 0.18033688011f;
    else if (kind == 1) v = wk[(n >> 3) * 512 + kp * 8 + (n & 7)];
    else if (kind == 2) v = wv[(n >> 3) * 512 + kp * 8 + (n & 7)];
    else if (kind == 3) v = projw[kn * 64 + n];
    else if (kind == 4) v = fc1w[kp * 256 + n];
    else                v = fc2w[(64 * (ks >> 1) + kp) * 64 + n];
    dst[jj] = f2bf(v);
  }
}

__global__ __launch_bounds__(256, 5) void block_fused(
    const float* __restrict__ x,
    const float* __restrict__ ln1w, const float* __restrict__ ln1b,
    const float* __restrict__ projb,
    const float* __restrict__ ln2w, const float* __restrict__ ln2b,
    const float* __restrict__ fc1b, const float* __restrict__ fc2b,
    const unsigned short* __restrict__ wsm, float* __restrict__ out) {
  __shared__ __attribute__((aligned(16))) unsigned short lds[LDS_TOT];

  const int tid  = threadIdx.x;
  const int w    = tid >> 6;     // wave 0..3 owns tokens 16w..16w+15 (QKV/proj/FF)
  const int lane = tid & 63;
  const int g    = lane >> 4;
  const int jl   = lane & 15;
  const size_t b = blockIdx.x;
  const float* xb = x + b * 4096;
  const f32x4 zf = {0.f, 0.f, 0.f, 0.f};

  const int myrow = 16 * w + jl;                 // this lane's token
  const int krow  = myrow * LR;                  // K region row
  const int qrow  = OFF_Q + myrow * LR;          // Q (-> attn) region row
  const int sigb  = 32 * (w >> 1) + 8 * g + 4 * (w & 1);  // sigma slot base for V

  if (tid < 40) ((unsigned*)(lds + ZROW))[tid] = 0u;   // zero row (pre-barrier)

  // ---------- LN1 fully in registers ----------
  float mean, rstd;
  unsigned hr[8];
  {
    f32x4 xw[4];
    float s = 0.f, ss = 0.f;
    #pragma unroll
    for (int mi = 0; mi < 4; ++mi) {
      xw[mi] = *(const f32x4*)(xb + myrow * 64 + 16 * mi + 4 * g);
      #pragma unroll
      for (int r = 0; r < 4; ++r) { s += xw[mi][r]; ss += xw[mi][r] * xw[mi][r]; }
    }
    s  += __shfl_xor(s, 16, 64);  s  += __shfl_xor(s, 32, 64);
    ss += __shfl_xor(ss, 16, 64); ss += __shfl_xor(ss, 32, 64);
    mean = s * 0.015625f;
    rstd = rsqrtf(ss * 0.015625f - mean * mean + 1e-5f);
    #pragma unroll
    for (int mi = 0; mi < 4; ++mi) {
      f32x4 lw = *(const f32x4*)(ln1w + 16 * mi + 4 * g);
      f32x4 lb = *(const f32x4*)(ln1b + 16 * mi + 4 * g);
      float o0 = (xw[mi][0] - mean) * rstd * lw[0] + lb[0];
      float o1 = (xw[mi][1] - mean) * rstd * lw[1] + lb[1];
      float o2 = (xw[mi][2] - mean) * rstd * lw[2] + lb[2];
      float o3 = (xw[mi][3] - mean) * rstd * lw[3] + lb[3];
      hr[2 * mi] = pk2(o0, o1); hr[2 * mi + 1] = pk2(o2, o3);
    }
  }
  bf16x8 hb0 = frag((u32x4){hr[0], hr[1], hr[2], hr[3]});   // pi-layout B-frag ks=0
  bf16x8 hb1 = frag((u32x4){hr[4], hr[5], hr[6], hr[7]});   // ks=1

  // ---------- QKV (rolled): Q->LDS, K->LDS, V->LDS VT (sigma slots) ----------
  #pragma clang loop unroll(disable)
  for (int mt = 0; mt < 4; ++mt) {
    const unsigned short* wq8 = wsm + (2 * mt) * 512 + lane * 8;
    bf16x8 aq0 = *(const bf16x8*)(wq8);
    bf16x8 aq1 = *(const bf16x8*)(wq8 + 512);
    bf16x8 ak0 = *(const bf16x8*)(wq8 + 8 * 512);
    bf16x8 ak1 = *(const bf16x8*)(wq8 + 9 * 512);
    bf16x8 bv0 = *(const bf16x8*)(wq8 + 16 * 512);
    bf16x8 bv1 = *(const bf16x8*)(wq8 + 17 * 512);
    f32x4 q = MFMA16(aq0, hb0, zf); q = MFMA16(aq1, hb1, q);
    *(u32x2*)(lds + qrow + 16 * mt + 4 * g) = (u32x2){pk2(q[0], q[1]), pk2(q[2], q[3])};
    f32x4 kk = MFMA16(ak0, hb0, zf); kk = MFMA16(ak1, hb1, kk);
    *(u32x2*)(lds + krow + 16 * mt + 4 * g) = (u32x2){pk2(kk[0], kk[1]), pk2(kk[2], kk[3])};
    // V non-swapped: lane holds V[16w+4g+r][16mt+jl] -> VT row 16mt+jl, sigma slot
    f32x4 vv = MFMA16(hb0, bv0, zf); vv = MFMA16(hb1, bv1, vv);
    *(u32x2*)(lds + OFF_VT + (16 * mt + jl) * LR + sigb) =
        (u32x2){pk2(vv[0], vv[1]), pk2(vv[2], vv[3])};
  }
  __syncthreads();   // barrier 1: publish Q, K, VT (Q now read cross-wave)

  // ---------- attention: wave w owns heads {2w, 2w+1}, all 4 q-tiles each ----------
  // Balanced: every wave does 20 score tiles (was 8..32) and the 10 per-head
  // score MFMAs are mutually independent (ILP), vs 8 serial head chains before.
  {
    const bool g0 = (g == 0), j8 = (jl < 8);
    const int ka0 = g0 ? ((0  + jl) * LR) : ZROW;   // K-operand row bases
    const int ka1 = g0 ? ((16 + jl) * LR) : ZROW;
    const int ka2 = g0 ? ((32 + jl) * LR) : ZROW;
    const int ka3 = g0 ? ((48 + jl) * LR) : ZROW;
    const int qb0 = g0 ? (OFF_Q + (0  + jl) * LR) : ZROW;   // Q-operand row bases
    const int qb1 = g0 ? (OFF_Q + (16 + jl) * LR) : ZROW;
    const int qb2 = g0 ? (OFF_Q + (32 + jl) * LR) : ZROW;
    const int qb3 = g0 ? (OFF_Q + (48 + jl) * LR) : ZROW;
    // diagonal causal masks (tile qt==mi): keep s<=q <=> 4g+r <= jl
    const bool m0 = (4 * g + 0 <= jl), m1 = (4 * g + 1 <= jl);
    const bool m2 = (4 * g + 2 <= jl), m3 = (4 * g + 3 <= jl);
    #pragma clang loop unroll(disable)
    for (int hh = 0; hh < 2; ++hh) {
      const int ho = 16 * w + 8 * hh;   // = 8 * head
      const int vbase = j8 ? (OFF_VT + (ho + jl) * LR) : ZROW;
      bf16x8 bq0 = *(const bf16x8*)(lds + qb0 + ho);
      bf16x8 bq1 = *(const bf16x8*)(lds + qb1 + ho);
      bf16x8 bq2 = *(const bf16x8*)(lds + qb2 + ho);
      bf16x8 bq3 = *(const bf16x8*)(lds + qb3 + ho);
      bf16x8 k0  = *(const bf16x8*)(lds + ka0 + ho);
      bf16x8 k1  = *(const bf16x8*)(lds + ka1 + ho);
      bf16x8 k2  = *(const bf16x8*)(lds + ka2 + ho);
      bf16x8 k3  = *(const bf16x8*)(lds + ka3 + ho);
      bf16x8 aw0 = *(const bf16x8*)(lds + vbase + 8 * g);
      bf16x8 aw1 = *(const bf16x8*)(lds + vbase + 32 + 8 * g);
      wfence();   // all head-h reads issue before the head-h dumps (cross-lane WAR)
      // ---- q-tiles 0,1 (3 score MFMAs) ----
      f32x4 s00 = MFMA16(k0, bq0, zf);
      f32x4 s10 = MFMA16(k0, bq1, zf);
      f32x4 s11 = MFMA16(k1, bq1, zf);
      {   // qt 0: diagonal tile only
        float e0 = m0 ? exp2f(s00[0]) : 0.f, e1 = m1 ? exp2f(s00[1]) : 0.f;
        float e2 = m2 ? exp2f(s00[2]) : 0.f, e3 = m3 ? exp2f(s00[3]) : 0.f;
        float sum = (e0 + e1) + (e2 + e3);
        sum += __shfl_xor(sum, 16, 64); sum += __shfl_xor(sum, 32, 64);
        float inv = __builtin_amdgcn_rcpf(sum);
        bf16x8 bp0 = frag((u32x4){pk2(e0, e1), pk2(e2, e3), 0u, 0u});
        f32x4 pv = MFMA16(aw0, bp0, zf);   // bp1 == 0 -> skip second MFMA
        if (g < 2)
          *(u32x2*)(lds + OFF_Q + jl * LR + ho + 4 * g) =
              (u32x2){pk2(pv[0] * inv, pv[1] * inv), pk2(pv[2] * inv, pv[3] * inv)};
      }
      {   // qt 1: full tile mi0 + diagonal mi1
        float a0 = exp2f(s10[0]), a1 = exp2f(s10[1]);
        float a2 = exp2f(s10[2]), a3 = exp2f(s10[3]);
        float e0 = m0 ? exp2f(s11[0]) : 0.f, e1 = m1 ? exp2f(s11[1]) : 0.f;
        float e2 = m2 ? exp2f(s11[2]) : 0.f, e3 = m3 ? exp2f(s11[3]) : 0.f;
        float sum = ((a0 + a1) + (a2 + a3)) + ((e0 + e1) + (e2 + e3));
        sum += __shfl_xor(sum, 16, 64); sum += __shfl_xor(sum, 32, 64);
        float inv = __builtin_amdgcn_rcpf(sum);
        bf16x8 bp0 = frag((u32x4){pk2(a0, a1), pk2(a2, a3), pk2(e0, e1), pk2(e2, e3)});
        f32x4 pv = MFMA16(aw0, bp0, zf);
        if (g < 2)
          *(u32x2*)(lds + OFF_Q + (16 + jl) * LR + ho + 4 * g) =
              (u32x2){pk2(pv[0] * inv, pv[1] * inv), pk2(pv[2] * inv, pv[3] * inv)};
      }
      // ---- q-tiles 2,3 (7 score MFMAs) ----
      f32x4 s20 = MFMA16(k0, bq2, zf);
      f32x4 s21 = MFMA16(k1, bq2, zf);
      f32x4 s22 = MFMA16(k2, bq2, zf);
      f32x4 s30 = MFMA16(k0, bq3, zf);
      f32x4 s31 = MFMA16(k1, bq3, zf);
      f32x4 s32 = MFMA16(k2, bq3, zf);
      f32x4 s33 = MFMA16(k3, bq3, zf);
      {   // qt 2: full mi0, mi1 + diagonal mi2
        float a0 = exp2f(s20[0]), a1 = exp2f(s20[1]);
        float a2 = exp2f(s20[2]), a3 = exp2f(s20[3]);
        float c0 = exp2f(s21[0]), c1 = exp2f(s21[1]);
        float c2 = exp2f(s21[2]), c3 = exp2f(s21[3]);
        float e0 = m0 ? exp2f(s22[0]) : 0.f, e1 = m1 ? exp2f(s22[1]) : 0.f;
        float e2 = m2 ? exp2f(s22[2]) : 0.f, e3 = m3 ? exp2f(s22[3]) : 0.f;
        float sum = ((a0 + a1) + (a2 + a3)) + ((c0 + c1) + (c2 + c3))
                  + ((e0 + e1) + (e2 + e3));
        sum += __shfl_xor(sum, 16, 64); sum += __shfl_xor(sum, 32, 64);
        float inv = __builtin_amdgcn_rcpf(sum);
        bf16x8 bp0 = frag((u32x4){pk2(a0, a1), pk2(a2, a3), pk2(c0, c1), pk2(c2, c3)});
        bf16x8 bp1 = frag((u32x4){pk2(e0, e1), pk2(e2, e3), 0u, 0u});
        f32x4 pv = MFMA16(aw0, bp0, zf); pv = MFMA16(aw1, bp1, pv);
        if (g < 2)
          *(u32x2*)(lds + OFF_Q + (32 + jl) * LR + ho + 4 * g) =
              (u32x2){pk2(pv[0] * inv, pv[1] * inv), pk2(pv[2] * inv, pv[3] * inv)};
      }
      {   // qt 3: full mi0..2 + diagonal mi3
        float a0 = exp2f(s30[0]), a1 = exp2f(s30[1]);
        float a2 = exp2f(s30[2]), a3 = exp2f(s30[3]);
        float c0 = exp2f(s31[0]), c1 = exp2f(s31[1]);
        float c2 = exp2f(s31[2]), c3 = exp2f(s31[3]);
        float d0 = exp2f(s32[0]), d1 = exp2f(s32[1]);
        float d2 = exp2f(s32[2]), d3 = exp2f(s32[3]);
        float e0 = m0 ? exp2f(s33[0]) : 0.f, e1 = m1 ? exp2f(s33[1]) : 0.f;
        float e2 = m2 ? exp2f(s33[2]) : 0.f, e3 = m3 ? exp2f(s33[3]) : 0.f;
        float sum = ((a0 + a1) + (a2 + a3)) + ((c0 + c1) + (c2 + c3))
                  + ((d0 + d1) + (d2 + d3)) + ((e0 + e1) + (e2 + e3));
        sum += __shfl_xor(sum, 16, 64); sum += __shfl_xor(sum, 32, 64);
        float inv = __builtin_amdgcn_rcpf(sum);
        bf16x8 bp0 = frag((u32x4){pk2(a0, a1), pk2(a2, a3), pk2(c0, c1), pk2(c2, c3)});
        bf16x8 bp1 = frag((u32x4){pk2(d0, d1), pk2(d2, d3), pk2(e0, e1), pk2(e2, e3)});
        f32x4 pv = MFMA16(aw0, bp0, zf); pv = MFMA16(aw1, bp1, pv);
        if (g < 2)
          *(u32x2*)(lds + OFF_Q + (48 + jl) * LR + ho + 4 * g) =
              (u32x2){pk2(pv[0] * inv, pv[1] * inv), pk2(pv[2] * inv, pv[3] * inv)};
      }
    }
  }
  __syncthreads();   // barrier 2: publish attn (dump rows are cross-wave)
  bf16x8 bat0 = *(const bf16x8*)(lds + qrow + 8 * g);
  bf16x8 bat1 = *(const bf16x8*)(lds + qrow + 32 + 8 * g);

  // ---------- proj (swapped, natural k) + residual; x2 in fp32 regs ----------
  f32x4 x2[4];
  #pragma unroll
  for (int mi = 0; mi < 4; ++mi) {
    bf16x8 a0 = *(const bf16x8*)(wsm + (24 + 2 * mi) * 512 + lane * 8);
    bf16x8 a1 = *(const bf16x8*)(wsm + (25 + 2 * mi) * 512 + lane * 8);
    f32x4 acc = MFMA16(a0, bat0, zf); acc = MFMA16(a1, bat1, acc);
    f32x4 xv = *(const f32x4*)(xb + myrow * 64 + 16 * mi + 4 * g);
    f32x4 pb = *(const f32x4*)(projb + 16 * mi + 4 * g);
    x2[mi] = xv + acc + pb;
  }

  // ---------- LN2 in registers ----------
  float mean2, rstd2;
  {
    float s = 0.f, ss = 0.f;
    #pragma unroll
    for (int mi = 0; mi < 4; ++mi)
      #pragma unroll
      for (int r = 0; r < 4; ++r) { s += x2[mi][r]; ss += x2[mi][r] * x2[mi][r]; }
    s  += __shfl_xor(s, 16, 64);  s  += __shfl_xor(s, 32, 64);
    ss += __shfl_xor(ss, 16, 64); ss += __shfl_xor(ss, 32, 64);
    mean2 = s * 0.015625f;
    rstd2 = rsqrtf(ss * 0.015625f - mean2 * mean2 + 1e-5f);
  }
  unsigned h2[8];
  #pragma unroll
  for (int mi = 0; mi < 4; ++mi) {
    f32x4 lw = *(const f32x4*)(ln2w + 16 * mi + 4 * g);
    f32x4 lb = *(const f32x4*)(ln2b + 16 * mi + 4 * g);
    float o0 = (x2[mi][0] - mean2) * rstd2 * lw[0] + lb[0];
    float o1 = (x2[mi][1] - mean2) * rstd2 * lw[1] + lb[1];
    float o2 = (x2[mi][2] - mean2) * rstd2 * lw[2] + lb[2];
    float o3 = (x2[mi][3] - mean2) * rstd2 * lw[3] + lb[3];
    h2[2 * mi] = pk2(o0, o1); h2[2 * mi + 1] = pk2(o2, o3);
  }
  bf16x8 hc0 = frag((u32x4){h2[0], h2[1], h2[2], h2[3]});
  bf16x8 hc1 = frag((u32x4){h2[4], h2[5], h2[6], h2[7]});

  // ---------- FF (rolled over 4 hidden-chunks), all registers ----------
  f32x4 acc2[4];
  #pragma unroll
  for (int mi = 0; mi < 4; ++mi) acc2[mi] = zf;
  #pragma clang loop unroll(disable)
  for (int c = 0; c < 4; ++c) {
    const unsigned short* w1c = wsm + (32 + 8 * c) * 512 + lane * 8;   // fc1 chunks
    const unsigned short* w2c = wsm + (64 + 2 * c) * 512 + lane * 8;   // fc2 chunks
    const float* b1c = fc1b + 64 * c + 4 * g;
    unsigned fr0, fr1, fr2, fr3, fr4, fr5, fr6, fr7;
    {
      bf16x8 a0 = *(const bf16x8*)(w1c);
      bf16x8 a1 = *(const bf16x8*)(w1c + 512);
      f32x4 acc = MFMA16(a0, hc0, zf); acc = MFMA16(a1, hc1, acc);
      f32x4 bb = *(const f32x4*)(b1c);
      fr0 = pk2(fmaxf(acc[0] + bb[0], 0.f), fmaxf(acc[1] + bb[1], 0.f));
      fr1 = pk2(fmaxf(acc[2] + bb[2], 0.f), fmaxf(acc[3] + bb[3], 0.f));
    }
    {
      bf16x8 a0 = *(const bf16x8*)(w1c + 2 * 512);
      bf16x8 a1 = *(const bf16x8*)(w1c + 3 * 512);
      f32x4 acc = MFMA16(a0, hc0, zf); acc = MFMA16(a1, hc1, acc);
      f32x4 bb = *(const f32x4*)(b1c + 16);
      fr2 = pk2(fmaxf(acc[0] + bb[0], 0.f), fmaxf(acc[1] + bb[1], 0.f));
      fr3 = pk2(fmaxf(acc[2] + bb[2], 0.f), fmaxf(acc[3] + bb[3], 0.f));
    }
    {
      bf16x8 a0 = *(const bf16x8*)(w1c + 4 * 512);
      bf16x8 a1 = *(const bf16x8*)(w1c + 5 * 512);
      f32x4 acc = MFMA16(a0, hc0, zf); acc = MFMA16(a1, hc1, acc);
      f32x4 bb = *(const f32x4*)(b1c + 32);
      fr4 = pk2(fmaxf(acc[0] + bb[0], 0.f), fmaxf(acc[1] + bb[1], 0.f));
      fr5 = pk2(fmaxf(acc[2] + bb[2], 0.f), fmaxf(acc[3] + bb[3], 0.f));
    }
    {
      bf16x8 a0 = *(const bf16x8*)(w1c + 6 * 512);
      bf16x8 a1 = *(const bf16x8*)(w1c + 7 * 512);
      f32x4 acc = MFMA16(a0, hc0, zf); acc = MFMA16(a1, hc1, acc);
      f32x4 bb = *(const f32x4*)(b1c + 48);
      fr6 = pk2(fmaxf(acc[0] + bb[0], 0.f), fmaxf(acc[1] + bb[1], 0.f));
      fr7 = pk2(fmaxf(acc[2] + bb[2], 0.f), fmaxf(acc[3] + bb[3], 0.f));
    }
    bf16x8 bf0 = frag((u32x4){fr0, fr1, fr2, fr3});
    bf16x8 bf1 = frag((u32x4){fr4, fr5, fr6, fr7});
    #pragma unroll
    for (int mi = 0; mi < 4; ++mi) {      // fc2 (swapped): accumulate cout tiles
      bf16x8 w20 = *(const bf16x8*)(w2c + (8 * mi) * 512);
      bf16x8 w21 = *(const bf16x8*)(w2c + (8 * mi + 1) * 512);
      acc2[mi] = MFMA16(w20, bf0, acc2[mi]);
      acc2[mi] = MFMA16(w21, bf1, acc2[mi]);
    }
  }

  // ---------- epilogue ----------
  {
    float* ob = out + b * 4096 + myrow * 64;
    #pragma unroll
    for (int mi = 0; mi < 4; ++mi) {
      f32x4 fb = *(const f32x4*)(fc2b + 16 * mi + 4 * g);
      f32x4 o = x2[mi] + acc2[mi] + fb;
      *(f32x4*)(ob + 16 * mi + 4 * g) = o;
    }
  }
}

extern "C" void kernel_launch(void* const* d_in, const int* in_sizes, int n_in,
                              void* d_out, int out_size, void* d_ws, size_t ws_size,
                              hipStream_t stream) {
  const float* x     = (const float*)d_in[0];
  const float* ln1w  = (const float*)d_in[1];
  const float* ln1b  = (const float*)d_in[2];
  const float* wq    = (const float*)d_in[3];
  const float* wk    = (const float*)d_in[4];
  const float* wvp   = (const float*)d_in[5];
  const float* projw = (const float*)d_in[6];
  const float* projb = (const float*)d_in[7];
  const float* ln2w  = (const float*)d_in[8];
  const float* ln2b  = (const float*)d_in[9];
  const float* fc1w  = (const float*)d_in[10];
  const float* fc1b  = (const float*)d_in[11];
  const float* fc2w  = (const float*)d_in[12];
  const float* fc2b  = (const float*)d_in[13];
  unsigned short* ws = (unsigned short*)d_ws;   // 96 KB repacked weights
  float* out = (float*)d_out;

  prep_weights<<<dim3(96), dim3(64), 0, stream>>>(wq, wk, wvp, projw, fc1w, fc2w, ws);

  int nblk = in_sizes[0] / 4096;
  block_fused<<<dim3(nblk), dim3(256), 0, stream>>>(
      x, ln1w, ln1b, projb, ln2w, ln2b, fc1b, fc2b, ws, out);
}

// Round 12
// 100.209 us; speedup vs baseline: 1.0649x; 1.0101x over previous
//
#include <hip/hip_runtime.h>

typedef __attribute__((ext_vector_type(8))) short bf16x8;
typedef __attribute__((ext_vector_type(4))) float f32x4;
typedef __attribute__((ext_vector_type(2))) unsigned int u32x2;
typedef __attribute__((ext_vector_type(4))) unsigned int u32x4;

__device__ __forceinline__ unsigned short f2bf(float f) {
  return __builtin_bit_cast(unsigned short, (__bf16)f);
}
__device__ __forceinline__ unsigned pk2(float a, float b) {
  return (unsigned)f2bf(a) | ((unsigned)f2bf(b) << 16);
}
__device__ __forceinline__ bf16x8 frag(u32x4 v) { return __builtin_bit_cast(bf16x8, v); }

#if __has_builtin(__builtin_amdgcn_exp2f)
#define EXP2(x) __builtin_amdgcn_exp2f(x)   // R7-proven: builtin handles trans-op hazard
#else
#define EXP2(x) exp2f(x)
#endif

// wave-level compiler memory fence (cross-lane LDS handoff within a wave)
__device__ __forceinline__ void wfence() {
  asm volatile("" ::: "memory");
  __builtin_amdgcn_wave_barrier();
}
// liveness pin: force v materialized here (issue-early loads; rule #17 idiom)
__device__ __forceinline__ void keepv(const bf16x8& v) { asm volatile("" :: "v"(v)); }
__device__ __forceinline__ void keepf(const f32x4& v) { asm volatile("" :: "v"(v)); }

#define MFMA16(a, b, c) __builtin_amdgcn_mfma_f32_16x16x32_bf16(a, b, c, 0, 0, 0)

#define LR 72            // 64-col rows, 144 B stride: 16B-aligned, bank-rotating
#define OFF_VT 4608      // K rows at 0; VT rows at 4608; Q (-> attn) rows at 9216
#define OFF_Q  9216
#define ZROW   13824     // 80-ushort zero row for disabled-lane operand reads
#define LDS_TOT 13904    // 27,808 B

// ---- weight prep (identical to R5..R11 -- numerically validated) ----
// pi k-permutation: slot(ks,g,j) -> source col 16*(2ks + (j>>2)) + 4g + (j&3).
// chunks (1 KB each): [0,8)=WqT(pi, x0.125*log2e) [8,16)=WkT(pi) [16,24)=Wv(pi)
// [24,32)=WpT(natural) [32,64)=W1T(pi) [64,96)=W2T(pi per 64-chunk)
__global__ void prep_weights(const float* __restrict__ wq, const float* __restrict__ wk,
                             const float* __restrict__ wv, const float* __restrict__ projw,
                             const float* __restrict__ fc1w, const float* __restrict__ fc2w,
                             unsigned short* __restrict__ ws) {
  int c = blockIdx.x, l = threadIdx.x;
  int g = l >> 4, jl = l & 15;
  int kind, T, ks;
  if (c < 8)       { kind = 0; T = c >> 1;        ks = c & 1; }
  else if (c < 16) { kind = 1; T = (c - 8) >> 1;  ks = (c - 8) & 1; }
  else if (c < 24) { kind = 2; T = (c - 16) >> 1; ks = (c - 16) & 1; }
  else if (c < 32) { kind = 3; T = (c - 24) >> 1; ks = (c - 24) & 1; }
  else if (c < 64) { kind = 4; T = (c - 32) >> 1; ks = (c - 32) & 1; }
  else             { kind = 5; T = (c - 64) >> 3; ks = (c - 64) & 7; }
  int n = 16 * T + jl;
  unsigned short* dst = ws + c * 512 + l * 8;
  #pragma unroll
  for (int jj = 0; jj < 8; ++jj) {
    int kp = 16 * (2 * (ks & 1) + (jj >> 2)) + 4 * g + (jj & 3);   // pi slot->col
    int kn = 32 * ks + 8 * g + jj;                                  // natural
    float v;
    if (kind == 0)      v = wq[(n >> 3) * 512 + kp * 8 + (n & 7)] * 0.18033688011f;
    else if (kind == 1) v = wk[(n >> 3) * 512 + kp * 8 + (n & 7)];
    else if (kind == 2) v = wv[(n >> 3) * 512 + kp * 8 + (n & 7)];
    else if (kind == 3) v = projw[kn * 64 + n];
    else if (kind == 4) v = fc1w[kp * 256 + n];
    else                v = fc2w[(64 * (ks >> 1) + kp) * 64 + n];
    dst[jj] = f2bf(v);
  }
}

__global__ __launch_bounds__(256, 4) void block_fused(
    const float* __restrict__ x,
    const float* __restrict__ ln1w, const float* __restrict__ ln1b,
    const float* __restrict__ projb,
    const float* __restrict__ ln2w, const float* __restrict__ ln2b,
    const float* __restrict__ fc1b, const float* __restrict__ fc2b,
    const unsigned short* __restrict__ wsm, float* __restrict__ out) {
  __shared__ __attribute__((aligned(16))) unsigned short lds[LDS_TOT];

  const int tid  = threadIdx.x;
  const int w    = tid >> 6;     // wave 0..3 owns tokens 16w..16w+15 (QKV/proj/FF)
  const int lane = tid & 63;
  const int g    = lane >> 4;
  const int jl   = lane & 15;
  const size_t b = blockIdx.x;
  const float* xb = x + b * 4096;
  const f32x4 zf = {0.f, 0.f, 0.f, 0.f};

  const int myrow = 16 * w + jl;                 // this lane's token
  const int krow  = myrow * LR;                  // K region row
  const int qrow  = OFF_Q + myrow * LR;          // Q (-> attn) region row
  const int sigb  = 32 * (w >> 1) + 8 * g + 4 * (w & 1);  // sigma slot base for V

  if (tid < 40) ((unsigned*)(lds + ZROW))[tid] = 0u;   // zero row (pre-barrier)

  // ---------- LN1 fully in registers; xw KEPT alive through proj ----------
  f32x4 xw[4];
  float mean, rstd;
  unsigned hr[8];
  {
    float s = 0.f, ss = 0.f;
    #pragma unroll
    for (int mi = 0; mi < 4; ++mi) {
      xw[mi] = *(const f32x4*)(xb + myrow * 64 + 16 * mi + 4 * g);
      #pragma unroll
      for (int r = 0; r < 4; ++r) { s += xw[mi][r]; ss += xw[mi][r] * xw[mi][r]; }
    }
    s  += __shfl_xor(s, 16, 64);  s  += __shfl_xor(s, 32, 64);
    ss += __shfl_xor(ss, 16, 64); ss += __shfl_xor(ss, 32, 64);
    mean = s * 0.015625f;
    rstd = rsqrtf(ss * 0.015625f - mean * mean + 1e-5f);
    #pragma unroll
    for (int mi = 0; mi < 4; ++mi) {
      f32x4 lw = *(const f32x4*)(ln1w + 16 * mi + 4 * g);
      f32x4 lb = *(const f32x4*)(ln1b + 16 * mi + 4 * g);
      float o0 = (xw[mi][0] - mean) * rstd * lw[0] + lb[0];
      float o1 = (xw[mi][1] - mean) * rstd * lw[1] + lb[1];
      float o2 = (xw[mi][2] - mean) * rstd * lw[2] + lb[2];
      float o3 = (xw[mi][3] - mean) * rstd * lw[3] + lb[3];
      hr[2 * mi] = pk2(o0, o1); hr[2 * mi + 1] = pk2(o2, o3);
    }
  }
  bf16x8 hb0 = frag((u32x4){hr[0], hr[1], hr[2], hr[3]});   // pi-layout B-frag ks=0
  bf16x8 hb1 = frag((u32x4){hr[4], hr[5], hr[6], hr[7]});   // ks=1

  // ---------- QKV (rolled): Q->LDS, K->LDS, V->LDS VT (sigma slots) ----------
  #pragma clang loop unroll(disable)
  for (int mt = 0; mt < 4; ++mt) {
    const unsigned short* wq8 = wsm + (2 * mt) * 512 + lane * 8;
    bf16x8 aq0 = *(const bf16x8*)(wq8);
    bf16x8 aq1 = *(const bf16x8*)(wq8 + 512);
    bf16x8 ak0 = *(const bf16x8*)(wq8 + 8 * 512);
    bf16x8 ak1 = *(const bf16x8*)(wq8 + 9 * 512);
    bf16x8 bv0 = *(const bf16x8*)(wq8 + 16 * 512);
    bf16x8 bv1 = *(const bf16x8*)(wq8 + 17 * 512);
    f32x4 q = MFMA16(aq0, hb0, zf); q = MFMA16(aq1, hb1, q);
    *(u32x2*)(lds + qrow + 16 * mt + 4 * g) = (u32x2){pk2(q[0], q[1]), pk2(q[2], q[3])};
    f32x4 kk = MFMA16(ak0, hb0, zf); kk = MFMA16(ak1, hb1, kk);
    *(u32x2*)(lds + krow + 16 * mt + 4 * g) = (u32x2){pk2(kk[0], kk[1]), pk2(kk[2], kk[3])};
    // V non-swapped: lane holds V[16w+4g+r][16mt+jl] -> VT row 16mt+jl, sigma slot
    f32x4 vv = MFMA16(hb0, bv0, zf); vv = MFMA16(hb1, bv1, vv);
    *(u32x2*)(lds + OFF_VT + (16 * mt + jl) * LR + sigb) =
        (u32x2){pk2(vv[0], vv[1]), pk2(vv[2], vv[3])};
  }
  __syncthreads();   // barrier 1: publish Q, K, VT (Q now read cross-wave)

  // ---------- attention: wave w owns heads {2w, 2w+1}, all 4 q-tiles each ----------
  {
    const bool g0 = (g == 0), j8 = (jl < 8);
    const int ka0 = g0 ? ((0  + jl) * LR) : ZROW;   // K-operand row bases
    const int ka1 = g0 ? ((16 + jl) * LR) : ZROW;
    const int ka2 = g0 ? ((32 + jl) * LR) : ZROW;
    const int ka3 = g0 ? ((48 + jl) * LR) : ZROW;
    const int qb0 = g0 ? (OFF_Q + (0  + jl) * LR) : ZROW;   // Q-operand row bases
    const int qb1 = g0 ? (OFF_Q + (16 + jl) * LR) : ZROW;
    const int qb2 = g0 ? (OFF_Q + (32 + jl) * LR) : ZROW;
    const int qb3 = g0 ? (OFF_Q + (48 + jl) * LR) : ZROW;
    // diagonal causal masks (tile qt==mi): keep s<=q <=> 4g+r <= jl
    const bool m0 = (4 * g + 0 <= jl), m1 = (4 * g + 1 <= jl);
    const bool m2 = (4 * g + 2 <= jl), m3 = (4 * g + 3 <= jl);
    #pragma clang loop unroll(disable)
    for (int hh = 0; hh < 2; ++hh) {
      const int ho = 16 * w + 8 * hh;   // = 8 * head
      const int vbase = j8 ? (OFF_VT + (ho + jl) * LR) : ZROW;
      bf16x8 bq0 = *(const bf16x8*)(lds + qb0 + ho);
      bf16x8 bq1 = *(const bf16x8*)(lds + qb1 + ho);
      bf16x8 bq2 = *(const bf16x8*)(lds + qb2 + ho);
      bf16x8 bq3 = *(const bf16x8*)(lds + qb3 + ho);
      bf16x8 k0  = *(const bf16x8*)(lds + ka0 + ho);
      bf16x8 k1  = *(const bf16x8*)(lds + ka1 + ho);
      bf16x8 k2  = *(const bf16x8*)(lds + ka2 + ho);
      bf16x8 k3  = *(const bf16x8*)(lds + ka3 + ho);
      bf16x8 aw0 = *(const bf16x8*)(lds + vbase + 8 * g);
      bf16x8 aw1 = *(const bf16x8*)(lds + vbase + 32 + 8 * g);
      wfence();   // all head-h reads issue before the head-h dumps (cross-lane WAR)
      // ---- q-tiles 0,1 (3 score MFMAs) ----
      f32x4 s00 = MFMA16(k0, bq0, zf);
      f32x4 s10 = MFMA16(k0, bq1, zf);
      f32x4 s11 = MFMA16(k1, bq1, zf);
      {   // qt 0: diagonal tile only
        float e0 = m0 ? EXP2(s00[0]) : 0.f, e1 = m1 ? EXP2(s00[1]) : 0.f;
        float e2 = m2 ? EXP2(s00[2]) : 0.f, e3 = m3 ? EXP2(s00[3]) : 0.f;
        float sum = (e0 + e1) + (e2 + e3);
        sum += __shfl_xor(sum, 16, 64); sum += __shfl_xor(sum, 32, 64);
        float inv = __builtin_amdgcn_rcpf(sum);
        bf16x8 bp0 = frag((u32x4){pk2(e0, e1), pk2(e2, e3), 0u, 0u});
        f32x4 pv = MFMA16(aw0, bp0, zf);
        if (g < 2)
          *(u32x2*)(lds + OFF_Q + jl * LR + ho + 4 * g) =
              (u32x2){pk2(pv[0] * inv, pv[1] * inv), pk2(pv[2] * inv, pv[3] * inv)};
      }
      {   // qt 1: full tile mi0 + diagonal mi1
        float a0 = EXP2(s10[0]), a1 = EXP2(s10[1]);
        float a2 = EXP2(s10[2]), a3 = EXP2(s10[3]);
        float e0 = m0 ? EXP2(s11[0]) : 0.f, e1 = m1 ? EXP2(s11[1]) : 0.f;
        float e2 = m2 ? EXP2(s11[2]) : 0.f, e3 = m3 ? EXP2(s11[3]) : 0.f;
        float sum = ((a0 + a1) + (a2 + a3)) + ((e0 + e1) + (e2 + e3));
        sum += __shfl_xor(sum, 16, 64); sum += __shfl_xor(sum, 32, 64);
        float inv = __builtin_amdgcn_rcpf(sum);
        bf16x8 bp0 = frag((u32x4){pk2(a0, a1), pk2(a2, a3), pk2(e0, e1), pk2(e2, e3)});
        f32x4 pv = MFMA16(aw0, bp0, zf);
        if (g < 2)
          *(u32x2*)(lds + OFF_Q + (16 + jl) * LR + ho + 4 * g) =
              (u32x2){pk2(pv[0] * inv, pv[1] * inv), pk2(pv[2] * inv, pv[3] * inv)};
      }
      // ---- q-tiles 2,3 (7 score MFMAs) ----
      f32x4 s20 = MFMA16(k0, bq2, zf);
      f32x4 s21 = MFMA16(k1, bq2, zf);
      f32x4 s22 = MFMA16(k2, bq2, zf);
      f32x4 s30 = MFMA16(k0, bq3, zf);
      f32x4 s31 = MFMA16(k1, bq3, zf);
      f32x4 s32 = MFMA16(k2, bq3, zf);
      f32x4 s33 = MFMA16(k3, bq3, zf);
      {   // qt 2: full mi0, mi1 + diagonal mi2
        float a0 = EXP2(s20[0]), a1 = EXP2(s20[1]);
        float a2 = EXP2(s20[2]), a3 = EXP2(s20[3]);
        float c0 = EXP2(s21[0]), c1 = EXP2(s21[1]);
        float c2 = EXP2(s21[2]), c3 = EXP2(s21[3]);
        float e0 = m0 ? EXP2(s22[0]) : 0.f, e1 = m1 ? EXP2(s22[1]) : 0.f;
        float e2 = m2 ? EXP2(s22[2]) : 0.f, e3 = m3 ? EXP2(s22[3]) : 0.f;
        float sum = ((a0 + a1) + (a2 + a3)) + ((c0 + c1) + (c2 + c3))
                  + ((e0 + e1) + (e2 + e3));
        sum += __shfl_xor(sum, 16, 64); sum += __shfl_xor(sum, 32, 64);
        float inv = __builtin_amdgcn_rcpf(sum);
        bf16x8 bp0 = frag((u32x4){pk2(a0, a1), pk2(a2, a3), pk2(c0, c1), pk2(c2, c3)});
        bf16x8 bp1 = frag((u32x4){pk2(e0, e1), pk2(e2, e3), 0u, 0u});
        f32x4 pv = MFMA16(aw0, bp0, zf); pv = MFMA16(aw1, bp1, pv);
        if (g < 2)
          *(u32x2*)(lds + OFF_Q + (32 + jl) * LR + ho + 4 * g) =
              (u32x2){pk2(pv[0] * inv, pv[1] * inv), pk2(pv[2] * inv, pv[3] * inv)};
      }
      {   // qt 3: full mi0..2 + diagonal mi3
        float a0 = EXP2(s30[0]), a1 = EXP2(s30[1]);
        float a2 = EXP2(s30[2]), a3 = EXP2(s30[3]);
        float c0 = EXP2(s31[0]), c1 = EXP2(s31[1]);
        float c2 = EXP2(s31[2]), c3 = EXP2(s31[3]);
        float d0 = EXP2(s32[0]), d1 = EXP2(s32[1]);
        float d2 = EXP2(s32[2]), d3 = EXP2(s32[3]);
        float e0 = m0 ? EXP2(s33[0]) : 0.f, e1 = m1 ? EXP2(s33[1]) : 0.f;
        float e2 = m2 ? EXP2(s33[2]) : 0.f, e3 = m3 ? EXP2(s33[3]) : 0.f;
        float sum = ((a0 + a1) + (a2 + a3)) + ((c0 + c1) + (c2 + c3))
                  + ((d0 + d1) + (d2 + d3)) + ((e0 + e1) + (e2 + e3));
        sum += __shfl_xor(sum, 16, 64); sum += __shfl_xor(sum, 32, 64);
        float inv = __builtin_amdgcn_rcpf(sum);
        bf16x8 bp0 = frag((u32x4){pk2(a0, a1), pk2(a2, a3), pk2(c0, c1), pk2(c2, c3)});
        bf16x8 bp1 = frag((u32x4){pk2(d0, d1), pk2(d2, d3), pk2(e0, e1), pk2(e2, e3)});
        f32x4 pv = MFMA16(aw0, bp0, zf); pv = MFMA16(aw1, bp1, pv);
        if (g < 2)
          *(u32x2*)(lds + OFF_Q + (48 + jl) * LR + ho + 4 * g) =
              (u32x2){pk2(pv[0] * inv, pv[1] * inv), pk2(pv[2] * inv, pv[3] * inv)};
      }
    }
  }

  // ---- T14 issue-early: proj weights + bias loads pinned BEFORE barrier 2 ----
  bf16x8 wp[8];
  f32x4 pbv[4];
  #pragma unroll
  for (int i = 0; i < 8; ++i) { wp[i] = *(const bf16x8*)(wsm + (24 + i) * 512 + lane * 8); keepv(wp[i]); }
  #pragma unroll
  for (int mi = 0; mi < 4; ++mi) { pbv[mi] = *(const f32x4*)(projb + 16 * mi + 4 * g); keepf(pbv[mi]); }
  __syncthreads();   // barrier 2: publish attn (dump rows are cross-wave)
  bf16x8 bat0 = *(const bf16x8*)(lds + qrow + 8 * g);
  bf16x8 bat1 = *(const bf16x8*)(lds + qrow + 32 + 8 * g);

  // ---------- proj (swapped, natural k) + residual from kept xw ----------
  f32x4 x2[4];
  #pragma unroll
  for (int mi = 0; mi < 4; ++mi) {
    f32x4 acc = MFMA16(wp[2 * mi], bat0, zf); acc = MFMA16(wp[2 * mi + 1], bat1, acc);
    x2[mi] = xw[mi] + acc + pbv[mi];
  }

  // ---- issue-early: FF chunk-0 fc1 weights pinned before LN2 ----
  bf16x8 f1p[8];
  #pragma unroll
  for (int i = 0; i < 8; ++i) { f1p[i] = *(const bf16x8*)(wsm + (32 + i) * 512 + lane * 8); keepv(f1p[i]); }

  // ---------- LN2 in registers ----------
  float mean2, rstd2;
  {
    float s = 0.f, ss = 0.f;
    #pragma unroll
    for (int mi = 0; mi < 4; ++mi)
      #pragma unroll
      for (int r = 0; r < 4; ++r) { s += x2[mi][r]; ss += x2[mi][r] * x2[mi][r]; }
    s  += __shfl_xor(s, 16, 64);  s  += __shfl_xor(s, 32, 64);
    ss += __shfl_xor(ss, 16, 64); ss += __shfl_xor(ss, 32, 64);
    mean2 = s * 0.015625f;
    rstd2 = rsqrtf(ss * 0.015625f - mean2 * mean2 + 1e-5f);
  }
  unsigned h2[8];
  #pragma unroll
  for (int mi = 0; mi < 4; ++mi) {
    f32x4 lw = *(const f32x4*)(ln2w + 16 * mi + 4 * g);
    f32x4 lb = *(const f32x4*)(ln2b + 16 * mi + 4 * g);
    float o0 = (x2[mi][0] - mean2) * rstd2 * lw[0] + lb[0];
    float o1 = (x2[mi][1] - mean2) * rstd2 * lw[1] + lb[1];
    float o2 = (x2[mi][2] - mean2) * rstd2 * lw[2] + lb[2];
    float o3 = (x2[mi][3] - mean2) * rstd2 * lw[3] + lb[3];
    h2[2 * mi] = pk2(o0, o1); h2[2 * mi + 1] = pk2(o2, o3);
  }
  bf16x8 hc0 = frag((u32x4){h2[0], h2[1], h2[2], h2[3]});
  bf16x8 hc1 = frag((u32x4){h2[4], h2[5], h2[6], h2[7]});

  // ---------- FF (rolled over 4 hidden-chunks), all registers ----------
  f32x4 acc2[4];
  #pragma unroll
  for (int mi = 0; mi < 4; ++mi) acc2[mi] = zf;
  #pragma clang loop unroll(disable)
  for (int c = 0; c < 4; ++c) {
    const unsigned short* w1c = wsm + (32 + 8 * c) * 512 + lane * 8;   // fc1 chunks
    const unsigned short* w2c = wsm + (64 + 2 * c) * 512 + lane * 8;   // fc2 chunks
    const float* b1c = fc1b + 64 * c + 4 * g;
    unsigned fr0, fr1, fr2, fr3, fr4, fr5, fr6, fr7;
    {
      bf16x8 a0 = (c == 0) ? f1p[0] : *(const bf16x8*)(w1c);
      bf16x8 a1 = (c == 0) ? f1p[1] : *(const bf16x8*)(w1c + 512);
      f32x4 acc = MFMA16(a0, hc0, zf); acc = MFMA16(a1, hc1, acc);
      f32x4 bb = *(const f32x4*)(b1c);
      fr0 = pk2(fmaxf(acc[0] + bb[0], 0.f), fmaxf(acc[1] + bb[1], 0.f));
      fr1 = pk2(fmaxf(acc[2] + bb[2], 0.f), fmaxf(acc[3] + bb[3], 0.f));
    }
    {
      bf16x8 a0 = (c == 0) ? f1p[2] : *(const bf16x8*)(w1c + 2 * 512);
      bf16x8 a1 = (c == 0) ? f1p[3] : *(const bf16x8*)(w1c + 3 * 512);
      f32x4 acc = MFMA16(a0, hc0, zf); acc = MFMA16(a1, hc1, acc);
      f32x4 bb = *(const f32x4*)(b1c + 16);
      fr2 = pk2(fmaxf(acc[0] + bb[0], 0.f), fmaxf(acc[1] + bb[1], 0.f));
      fr3 = pk2(fmaxf(acc[2] + bb[2], 0.f), fmaxf(acc[3] + bb[3], 0.f));
    }
    {
      bf16x8 a0 = (c == 0) ? f1p[4] : *(const bf16x8*)(w1c + 4 * 512);
      bf16x8 a1 = (c == 0) ? f1p[5] : *(const bf16x8*)(w1c + 5 * 512);
      f32x4 acc = MFMA16(a0, hc0, zf); acc = MFMA16(a1, hc1, acc);
      f32x4 bb = *(const f32x4*)(b1c + 32);
      fr4 = pk2(fmaxf(acc[0] + bb[0], 0.f), fmaxf(acc[1] + bb[1], 0.f));
      fr5 = pk2(fmaxf(acc[2] + bb[2], 0.f), fmaxf(acc[3] + bb[3], 0.f));
    }
    {
      bf16x8 a0 = (c == 0) ? f1p[6] : *(const bf16x8*)(w1c + 6 * 512);
      bf16x8 a1 = (c == 0) ? f1p[7] : *(const bf16x8*)(w1c + 7 * 512);
      f32x4 acc = MFMA16(a0, hc0, zf); acc = MFMA16(a1, hc1, acc);
      f32x4 bb = *(const f32x4*)(b1c + 48);
      fr6 = pk2(fmaxf(acc[0] + bb[0], 0.f), fmaxf(acc[1] + bb[1], 0.f));
      fr7 = pk2(fmaxf(acc[2] + bb[2], 0.f), fmaxf(acc[3] + bb[3], 0.f));
    }
    bf16x8 bf0 = frag((u32x4){fr0, fr1, fr2, fr3});
    bf16x8 bf1 = frag((u32x4){fr4, fr5, fr6, fr7});
    #pragma unroll
    for (int mi = 0; mi < 4; ++mi) {      // fc2 (swapped): accumulate cout tiles
      bf16x8 w20 = *(const bf16x8*)(w2c + (8 * mi) * 512);
      bf16x8 w21 = *(const bf16x8*)(w2c + (8 * mi + 1) * 512);
      acc2[mi] = MFMA16(w20, bf0, acc2[mi]);
      acc2[mi] = MFMA16(w21, bf1, acc2[mi]);
    }
  }

  // ---------- epilogue ----------
  {
    float* ob = out + b * 4096 + myrow * 64;
    #pragma unroll
    for (int mi = 0; mi < 4; ++mi) {
      f32x4 fb = *(const f32x4*)(fc2b + 16 * mi + 4 * g);
      f32x4 o = x2[mi] + acc2[mi] + fb;
      *(f32x4*)(ob + 16 * mi + 4 * g) = o;
    }
  }
}

extern "C" void kernel_launch(void* const* d_in, const int* in_sizes, int n_in,
                              void* d_out, int out_size, void* d_ws, size_t ws_size,
                              hipStream_t stream) {
  const float* x     = (const float*)d_in[0];
  const float* ln1w  = (const float*)d_in[1];
  const float* ln1b  = (const float*)d_in[2];
  const float* wq    = (const float*)d_in[3];
  const float* wk    = (const float*)d_in[4];
  const float* wvp   = (const float*)d_in[5];
  const float* projw = (const float*)d_in[6];
  const float* projb = (const float*)d_in[7];
  const float* ln2w  = (const float*)d_in[8];
  const float* ln2b  = (const float*)d_in[9];
  const float* fc1w  = (const float*)d_in[10];
  const float* fc1b  = (const float*)d_in[11];
  const float* fc2w  = (const float*)d_in[12];
  const float* fc2b  = (const float*)d_in[13];
  unsigned short* ws = (unsigned short*)d_ws;   // 96 KB repacked weights
  float* out = (float*)d_out;

  prep_weights<<<dim3(96), dim3(64), 0, stream>>>(wq, wk, wvp, projw, fc1w, fc2w, ws);

  int nblk = in_sizes[0] / 4096;
  block_fused<<<dim3(nblk), dim3(256), 0, stream>>>(
      x, ln1w, ln1b, projb, ln2w, ln2b, fc1b, fc2b, ws, out);
}